// Round 4
// baseline (130.832 us; speedup 1.0000x reference)
//
#include <hip/hip_runtime.h>
#include <hip/hip_bf16.h>
#include <math.h>

constexpr int B_  = 2048;
constexpr int S_  = 16;
constexpr int D_  = 512;
constexpr int CH_ = 1024;

typedef __attribute__((ext_vector_type(8))) short bf16x8;
typedef __attribute__((ext_vector_type(4))) float f32x4;

// ---------------- workspace layout ----------------
constexpr size_t CNT_OFF  = 0;                                  // 16 ints
constexpr size_t NT_OFF   = 64;                                 // 1 int
constexpr size_t TL_OFF   = 128;                                // 64 ints
constexpr size_t LIST_OFF = 512;                                // 16*2048 ints = 128 KB
constexpr size_t XGT_OFF  = LIST_OFF + (size_t)16 * 2048 * 4;   // 2 MB bf16 [B][D]
constexpr size_t XGR_OFF  = XGT_OFF + (size_t)B_ * D_ * 2;      // 2 MB bf16 [B][D]

static __device__ __forceinline__ short f2bf(float x) {
    __hip_bfloat16 h = __float2bfloat16(x);
    return *(short*)&h;
}
static __device__ __forceinline__ float gelu_exact(float x) {
    return 0.5f * x * (1.f + erff(x * 0.70710678118654752f));
}

// ---------------- kernel 1: router + log_softmax + argmax + compaction + x gather ----------------
__global__ __launch_bounds__(1024) void k_router_sm(
    const float* __restrict__ ldt, const float* __restrict__ ldr,
    const float* __restrict__ w,   const float* __restrict__ bsc,
    float* __restrict__ sld, int* __restrict__ count, int* __restrict__ list,
    unsigned short* __restrict__ xgt, unsigned short* __restrict__ xgr)
{
    const int b    = blockIdx.x;
    const int wave = threadIdx.x >> 6;
    const int lane = threadIdx.x & 63;

    __shared__ float lgs[S_];
    __shared__ int   smi;

    const float4* pt = (const float4*)(ldt + ((size_t)b * S_ + wave) * D_);
    const float4* pr = (const float4*)(ldr + ((size_t)b * S_ + wave) * D_);
    const float4* wt = (const float4*)(w);
    const float4* wr = (const float4*)(w + D_);

    float acc = 0.f;
    #pragma unroll
    for (int it = 0; it < 2; it++) {
        const int i = lane + it * 64;
        float4 a  = pt[i]; float4 ww = wt[i];
        acc += a.x * ww.x + a.y * ww.y + a.z * ww.z + a.w * ww.w;
        float4 c  = pr[i]; float4 w2 = wr[i];
        acc += c.x * w2.x + c.y * w2.y + c.z * w2.z + c.w * w2.w;
    }
    #pragma unroll
    for (int off = 32; off > 0; off >>= 1) acc += __shfl_down(acc, off, 64);
    if (lane == 0) lgs[wave] = acc;
    __syncthreads();

    if (threadIdx.x < S_) {
        const int s = threadIdx.x;
        const float v = lgs[s] + bsc[0];
        float mv = v; int mi = s;
        #pragma unroll
        for (int d = 1; d < 16; d <<= 1) {
            float ov = __shfl_xor(mv, d, 16);
            int   oi = __shfl_xor(mi, d, 16);
            if (ov > mv || (ov == mv && oi < mi)) { mv = ov; mi = oi; }
        }
        float sum = expf(v - mv);
        #pragma unroll
        for (int d = 1; d < 16; d <<= 1) sum += __shfl_xor(sum, d, 16);
        const float lse = mv + logf(sum);
        sld[b * S_ + s] = v - lse;
        if (s == 0) {
            smi = mi;
            const int pos = atomicAdd(&count[mi], 1);
            list[mi * B_ + pos] = b;
        }
    }
    __syncthreads();

    // gather selected rows -> compact bf16 buffers
    const int mi = smi;
    const int t = threadIdx.x;
    if (t < D_) {
        xgt[(size_t)b * D_ + t] = (unsigned short)f2bf(ldt[((size_t)b * S_ + mi) * D_ + t]);
    } else {
        const int t2 = t - D_;
        xgr[(size_t)b * D_ + t2] = (unsigned short)f2bf(ldr[((size_t)b * S_ + mi) * D_ + t2]);
    }
}

// ---------------- kernel 2: tile-list compaction (1 thread) ----------------
__global__ void k_tiles(const int* __restrict__ count, int* __restrict__ ntile,
                        int* __restrict__ tlist)
{
    if (threadIdx.x == 0 && blockIdx.x == 0) {
        int nt = 0;
        for (int m = 0; m < S_; m++) {
            const int c = count[m];
            const int nst = (c + 63) >> 6;
            for (int s2 = 0; s2 < nst; s2++) tlist[nt++] = m | (s2 << 8);
        }
        ntile[0] = nt;
    }
}

// ---------------- kernel 3: expert heads — barrier-free direct-load MFMA ----------------
// bid = t(6) | head(1) | ct(4);  t = tile index into tlist
__global__ __launch_bounds__(256) void k_expert(
    const float* __restrict__ Wht, const float* __restrict__ bht,
    const float* __restrict__ Wot, const float* __restrict__ bot,
    const float* __restrict__ Whr, const float* __restrict__ bhr,
    const float* __restrict__ Wor, const float* __restrict__ bor,
    const unsigned short* __restrict__ xgt, const unsigned short* __restrict__ xgr,
    const int* __restrict__ count, const int* __restrict__ list,
    const int* __restrict__ ntile, const int* __restrict__ tlist,
    float* __restrict__ pose)
{
    const int bid  = blockIdx.x;
    const int ct   = bid & 15;
    const int head = (bid >> 4) & 1;
    const int t    = bid >> 5;
    if (t >= ntile[0]) return;
    const int tv = tlist[t];
    const int m  = tv & 255;
    const int st = tv >> 8;
    const int n  = count[m];

    const unsigned short* __restrict__ xg = head ? xgr : xgt;
    const float* __restrict__ Wh = head ? Whr : Wht;
    const float* __restrict__ bh = head ? bhr : bht;
    const float* __restrict__ Wo = head ? Wor : Wot;
    const float* __restrict__ bo = head ? bor : bot;
    const int noj    = head ? 4 : 3;
    const int jobase = head ? 3 : 0;

    const int tid  = threadIdx.x;
    const int wave = tid >> 6;
    const int lane = tid & 63;
    const int wr = wave >> 1, wc = wave & 1;
    const int l15 = lane & 15, lq = lane >> 4;
    const int rbase = st * 64 + wr * 32;   // global sample-slot base of this wave
    const int cb    = ct * 64 + wc * 32;   // global ch base of this wave

    // A row pointers in MFMA layout (row = l15, k-chunk = lq baked in)
    const unsigned short* arow[2];
    #pragma unroll
    for (int fm = 0; fm < 2; fm++) {
        const int gi = rbase + fm * 16 + l15;
        const int bb = (gi < n) ? list[m * B_ + gi] : 0;   // clamp tail rows to row 0
        arow[fm] = xg + (size_t)bb * D_ + lq * 8;
    }
    // B column pointer in MFMA layout (ch = l15, k-chunk = lq baked in)
    const float* wcol = Wh + (size_t)m * D_ * CH_ + (size_t)(lq * 8) * CH_ + cb + l15;

    f32x4 acc[2][2] = {};
    #pragma unroll 4
    for (int kk = 0; kk < D_; kk += 32) {
        bf16x8 a[2];
        a[0] = *(const bf16x8*)(arow[0] + kk);
        a[1] = *(const bf16x8*)(arow[1] + kk);
        bf16x8 bv[2];
        #pragma unroll
        for (int fn = 0; fn < 2; fn++) {
            const float* p = wcol + (size_t)kk * CH_ + fn * 16;
            short tmp[8];
            #pragma unroll
            for (int j = 0; j < 8; j++) tmp[j] = f2bf(p[(size_t)j * CH_]);
            bv[fn] = *(bf16x8*)tmp;
        }
        #pragma unroll
        for (int fm = 0; fm < 2; fm++)
            #pragma unroll
            for (int fn = 0; fn < 2; fn++)
                acc[fm][fn] = __builtin_amdgcn_mfma_f32_16x16x32_bf16(a[fm], bv[fn], acc[fm][fn], 0, 0, 0);
    }

    // ---- epilogue: bias + GELU + Wo partial + 16-lane reduce + atomicAdd ----
    float g[2][2][4];
    float wo_l[2][4];
    #pragma unroll
    for (int fn = 0; fn < 2; fn++) {
        const int ch = cb + fn * 16 + l15;
        const float bias = bh[m * CH_ + ch];
        #pragma unroll
        for (int fm = 0; fm < 2; fm++)
            #pragma unroll
            for (int j = 0; j < 4; j++)
                g[fm][fn][j] = gelu_exact(acc[fm][fn][j] + bias);
        #pragma unroll
        for (int jo = 0; jo < 4; jo++)
            wo_l[fn][jo] = (jo < noj) ? Wo[(size_t)(m * CH_ + ch) * noj + jo] : 0.f;
    }

    #pragma unroll
    for (int fm = 0; fm < 2; fm++) {
        #pragma unroll
        for (int j = 0; j < 4; j++) {
            #pragma unroll
            for (int jo = 0; jo < 4; jo++) {
                if (jo >= noj) continue;
                float v = g[fm][0][j] * wo_l[0][jo] + g[fm][1][j] * wo_l[1][jo];
                #pragma unroll
                for (int d = 1; d < 16; d <<= 1) v += __shfl_xor(v, d, 16);
                if (l15 == 0) {
                    const int gi = rbase + fm * 16 + lq * 4 + j;
                    if (gi < n) {
                        const int bb = list[m * B_ + gi];
                        if (ct == 0 && wc == 0) v += bo[m * noj + jo];
                        atomicAdd(&pose[(size_t)bb * 7 + jobase + jo], v);
                    }
                }
            }
        }
    }
}

// ---------------- launch ----------------
extern "C" void kernel_launch(void* const* d_in, const int* in_sizes, int n_in,
                              void* d_out, int out_size, void* d_ws, size_t ws_size,
                              hipStream_t stream)
{
    const float* ldt = (const float*)d_in[0];
    const float* ldr = (const float*)d_in[1];
    const float* wsc = (const float*)d_in[2];
    const float* bsc = (const float*)d_in[3];
    const float* Wht = (const float*)d_in[4];
    const float* bht = (const float*)d_in[5];
    const float* Wot = (const float*)d_in[6];
    const float* bot = (const float*)d_in[7];
    const float* Whr = (const float*)d_in[8];
    const float* bhr = (const float*)d_in[9];
    const float* Wor = (const float*)d_in[10];
    const float* bor = (const float*)d_in[11];

    float* pose = (float*)d_out;                   // [B,7]
    float* sld  = (float*)d_out + (size_t)B_ * 7;  // [B,16]

    int* count = (int*)((char*)d_ws + CNT_OFF);
    int* ntile = (int*)((char*)d_ws + NT_OFF);
    int* tlist = (int*)((char*)d_ws + TL_OFF);
    int* list  = (int*)((char*)d_ws + LIST_OFF);
    unsigned short* xgt = (unsigned short*)((char*)d_ws + XGT_OFF);
    unsigned short* xgr = (unsigned short*)((char*)d_ws + XGR_OFF);

    hipMemsetAsync(count, 0, 16 * sizeof(int), stream);
    hipMemsetAsync(pose, 0, (size_t)B_ * 7 * sizeof(float), stream);

    // 1) router + softmax + argmax + compaction + bf16 gather
    k_router_sm<<<dim3(B_), dim3(1024), 0, stream>>>(
        ldt, ldr, wsc, bsc, sld, count, list, xgt, xgr);

    // 2) compact tile list (<= 48 tiles)
    k_tiles<<<dim3(1), dim3(64), 0, stream>>>(count, ntile, tlist);

    // 3) expert heads: grid = 48 tile slots x 2 heads x 16 ch-tiles
    k_expert<<<dim3(48 * 2 * 16), dim3(256), 0, stream>>>(
        Wht, bht, Wot, bot, Whr, bhr, Wor, bor,
        xgt, xgr, count, list, ntile, tlist, pose);
}

// Round 5
// 119.745 us; speedup vs baseline: 1.0926x; 1.0926x over previous
//
#include <hip/hip_runtime.h>
#include <hip/hip_bf16.h>
#include <math.h>

constexpr int B_  = 2048;
constexpr int S_  = 16;
constexpr int D_  = 512;
constexpr int CH_ = 1024;

typedef __attribute__((ext_vector_type(8))) short bf16x8;
typedef __attribute__((ext_vector_type(4))) float f32x4;

// ---------------- workspace layout ----------------
constexpr size_t CNT_OFF  = 0;                                  // 16 ints
constexpr size_t LIST_OFF = 512;                                // 16*2048 ints = 128 KB
constexpr size_t XGT_OFF  = LIST_OFF + (size_t)16 * 2048 * 4;   // 2 MB bf16 [B][D]
constexpr size_t XGR_OFF  = XGT_OFF + (size_t)B_ * D_ * 2;      // 2 MB bf16 [B][D]

static __device__ __forceinline__ short f2bf(float x) {
    __hip_bfloat16 h = __float2bfloat16(x);
    return *(short*)&h;
}
static __device__ __forceinline__ float gelu_exact(float x) {
    return 0.5f * x * (1.f + erff(x * 0.70710678118654752f));
}

// ---------------- kernel 1: router + log_softmax + argmax + compaction + x gather ----------------
__global__ __launch_bounds__(1024) void k_router_sm(
    const float* __restrict__ ldt, const float* __restrict__ ldr,
    const float* __restrict__ w,   const float* __restrict__ bsc,
    float* __restrict__ sld, int* __restrict__ count, int* __restrict__ list,
    unsigned short* __restrict__ xgt, unsigned short* __restrict__ xgr)
{
    const int b    = blockIdx.x;
    const int wave = threadIdx.x >> 6;
    const int lane = threadIdx.x & 63;

    __shared__ float lgs[S_];
    __shared__ int   smi;

    const float4* pt = (const float4*)(ldt + ((size_t)b * S_ + wave) * D_);
    const float4* pr = (const float4*)(ldr + ((size_t)b * S_ + wave) * D_);
    const float4* wt = (const float4*)(w);
    const float4* wr = (const float4*)(w + D_);

    float acc = 0.f;
    #pragma unroll
    for (int it = 0; it < 2; it++) {
        const int i = lane + it * 64;
        float4 a  = pt[i]; float4 ww = wt[i];
        acc += a.x * ww.x + a.y * ww.y + a.z * ww.z + a.w * ww.w;
        float4 c  = pr[i]; float4 w2 = wr[i];
        acc += c.x * w2.x + c.y * w2.y + c.z * w2.z + c.w * w2.w;
    }
    #pragma unroll
    for (int off = 32; off > 0; off >>= 1) acc += __shfl_down(acc, off, 64);
    if (lane == 0) lgs[wave] = acc;
    __syncthreads();

    if (threadIdx.x < S_) {
        const int s = threadIdx.x;
        const float v = lgs[s] + bsc[0];
        float mv = v; int mi = s;
        #pragma unroll
        for (int d = 1; d < 16; d <<= 1) {
            float ov = __shfl_xor(mv, d, 16);
            int   oi = __shfl_xor(mi, d, 16);
            if (ov > mv || (ov == mv && oi < mi)) { mv = ov; mi = oi; }
        }
        float sum = expf(v - mv);
        #pragma unroll
        for (int d = 1; d < 16; d <<= 1) sum += __shfl_xor(sum, d, 16);
        const float lse = mv + logf(sum);
        sld[b * S_ + s] = v - lse;
        if (s == 0) {
            smi = mi;
            const int pos = atomicAdd(&count[mi], 1);
            list[mi * B_ + pos] = b;
        }
    }
    __syncthreads();

    const int mi = smi;
    const int t = threadIdx.x;
    if (t < D_) {
        xgt[(size_t)b * D_ + t] = (unsigned short)f2bf(ldt[((size_t)b * S_ + mi) * D_ + t]);
    } else {
        const int t2 = t - D_;
        xgr[(size_t)b * D_ + t2] = (unsigned short)f2bf(ldr[((size_t)b * S_ + mi) * D_ + t2]);
    }
}

// ---------------- kernel 2: expert heads — weight-stationary register MFMA ----------------
// bid = m(4) | head(1) | ct(4);  block covers 64 ch of expert m, loops all its sample tiles
__global__ __launch_bounds__(256) void k_expert(
    const float* __restrict__ Wht, const float* __restrict__ bht,
    const float* __restrict__ Wot, const float* __restrict__ bot,
    const float* __restrict__ Whr, const float* __restrict__ bhr,
    const float* __restrict__ Wor, const float* __restrict__ bor,
    const unsigned short* __restrict__ xgt, const unsigned short* __restrict__ xgr,
    const int* __restrict__ count, const int* __restrict__ list,
    float* __restrict__ pose)
{
    const int bid  = blockIdx.x;
    const int ct   = bid & 15;
    const int head = (bid >> 4) & 1;
    const int m    = bid >> 5;
    const int n    = count[m];
    if (n == 0) return;

    const unsigned short* __restrict__ xg = head ? xgr : xgt;
    const float* __restrict__ Wh = head ? Whr : Wht;
    const float* __restrict__ bh = head ? bhr : bht;
    const float* __restrict__ Wo = head ? Wor : Wot;
    const float* __restrict__ bo = head ? bor : bot;
    const int noj    = head ? 4 : 3;
    const int jobase = head ? 3 : 0;

    const int tid  = threadIdx.x;
    const int wave = tid >> 6;
    const int lane = tid & 63;
    const int l15  = lane & 15;
    const int lq   = lane >> 4;
    const int ch   = ct * 64 + wave * 16 + l15;   // this lane's channel

    __shared__ float ored[64][4];

    // ---- phase 1: load this lane's full-K weight column into registers (once) ----
    const float* wp = Wh + (size_t)m * D_ * CH_ + (size_t)(lq * 8) * CH_ + ch;
    bf16x8 breg[16];
    #pragma unroll
    for (int t = 0; t < 16; t++) {
        short tmp[8];
        #pragma unroll
        for (int j = 0; j < 8; j++)
            tmp[j] = f2bf(wp[(size_t)(t * 32 + j) * CH_]);
        breg[t] = *(bf16x8*)tmp;
    }
    const float bias = bh[m * CH_ + ch];
    float wo_l[4];
    #pragma unroll
    for (int jo = 0; jo < 4; jo++)
        wo_l[jo] = (jo < noj) ? Wo[(size_t)(m * CH_ + ch) * noj + jo] : 0.f;

    // ---- phase 2: loop over this expert's sample tiles ----
    const int nst = (n + 63) >> 6;
    for (int st = 0; st < nst; st++) {
        // zero LDS reduction buffer
        ((float*)ored)[tid] = 0.f;   // 256 floats = 64*4
        __syncthreads();

        const int base = st * 64;
        const unsigned short* arow[4];
        #pragma unroll
        for (int fm = 0; fm < 4; fm++) {
            const int gi = base + fm * 16 + l15;
            const int bb = (gi < n) ? list[m * B_ + gi] : 0;
            arow[fm] = xg + (size_t)bb * D_ + lq * 8;
        }

        f32x4 acc[4] = {};
        #pragma unroll
        for (int t = 0; t < 16; t++) {
            bf16x8 a0 = *(const bf16x8*)(arow[0] + t * 32);
            bf16x8 a1 = *(const bf16x8*)(arow[1] + t * 32);
            bf16x8 a2 = *(const bf16x8*)(arow[2] + t * 32);
            bf16x8 a3 = *(const bf16x8*)(arow[3] + t * 32);
            acc[0] = __builtin_amdgcn_mfma_f32_16x16x32_bf16(a0, breg[t], acc[0], 0, 0, 0);
            acc[1] = __builtin_amdgcn_mfma_f32_16x16x32_bf16(a1, breg[t], acc[1], 0, 0, 0);
            acc[2] = __builtin_amdgcn_mfma_f32_16x16x32_bf16(a2, breg[t], acc[2], 0, 0, 0);
            acc[3] = __builtin_amdgcn_mfma_f32_16x16x32_bf16(a3, breg[t], acc[3], 0, 0, 0);
        }

        // epilogue: GELU + Wo partial, 16-lane shuffle reduce, LDS combine
        #pragma unroll
        for (int fm = 0; fm < 4; fm++) {
            #pragma unroll
            for (int j = 0; j < 4; j++) {
                const float g = gelu_exact(acc[fm][j] + bias);
                #pragma unroll
                for (int jo = 0; jo < 4; jo++) {
                    if (jo >= noj) continue;
                    float v = g * wo_l[jo];
                    #pragma unroll
                    for (int d = 1; d < 16; d <<= 1) v += __shfl_xor(v, d, 16);
                    if (l15 == 0)
                        atomicAdd(&ored[fm * 16 + lq * 4 + j][jo], v);
                }
            }
        }
        __syncthreads();

        // drain: one global atomic per (row, jo) per block
        if (tid < 64 * 4) {
            const int rl = tid >> 2;
            const int jo = tid & 3;
            const int gi = base + rl;
            if (jo < noj && gi < n) {
                const int bb = list[m * B_ + gi];
                float v = ored[rl][jo];
                if (ct == 0) v += bo[m * noj + jo];
                atomicAdd(&pose[(size_t)bb * 7 + jobase + jo], v);
            }
        }
        __syncthreads();
    }
}

// ---------------- launch ----------------
extern "C" void kernel_launch(void* const* d_in, const int* in_sizes, int n_in,
                              void* d_out, int out_size, void* d_ws, size_t ws_size,
                              hipStream_t stream)
{
    const float* ldt = (const float*)d_in[0];
    const float* ldr = (const float*)d_in[1];
    const float* wsc = (const float*)d_in[2];
    const float* bsc = (const float*)d_in[3];
    const float* Wht = (const float*)d_in[4];
    const float* bht = (const float*)d_in[5];
    const float* Wot = (const float*)d_in[6];
    const float* bot = (const float*)d_in[7];
    const float* Whr = (const float*)d_in[8];
    const float* bhr = (const float*)d_in[9];
    const float* Wor = (const float*)d_in[10];
    const float* bor = (const float*)d_in[11];

    float* pose = (float*)d_out;                   // [B,7]
    float* sld  = (float*)d_out + (size_t)B_ * 7;  // [B,16]

    int* count = (int*)((char*)d_ws + CNT_OFF);
    int* list  = (int*)((char*)d_ws + LIST_OFF);
    unsigned short* xgt = (unsigned short*)((char*)d_ws + XGT_OFF);
    unsigned short* xgr = (unsigned short*)((char*)d_ws + XGR_OFF);

    hipMemsetAsync(count, 0, 16 * sizeof(int), stream);
    hipMemsetAsync(pose, 0, (size_t)B_ * 7 * sizeof(float), stream);

    // 1) router + softmax + argmax + compaction + bf16 gather
    k_router_sm<<<dim3(B_), dim3(1024), 0, stream>>>(
        ldt, ldr, wsc, bsc, sld, count, list, xgt, xgr);

    // 2) expert heads: weight-stationary, grid = m(16) x head(2) x ct(16) = 512 blocks
    k_expert<<<dim3(16 * 2 * 16), dim3(256), 0, stream>>>(
        Wht, bht, Wot, bot, Whr, bhr, Wor, bor,
        xgt, xgr, count, list, pose);
}

// Round 6
// 112.889 us; speedup vs baseline: 1.1589x; 1.0607x over previous
//
#include <hip/hip_runtime.h>
#include <hip/hip_bf16.h>
#include <math.h>

constexpr int B_  = 2048;
constexpr int S_  = 16;
constexpr int D_  = 512;
constexpr int CH_ = 1024;

typedef __attribute__((ext_vector_type(8))) short bf16x8;
typedef __attribute__((ext_vector_type(4))) float f32x4;

// ---------------- workspace layout ----------------
constexpr size_t CNT_OFF  = 0;                                  // 16 ints
constexpr size_t NT_OFF   = 64;                                 // 1 int
constexpr size_t TL_OFF   = 128;                                // 64 ints
constexpr size_t LIST_OFF = 512;                                // 16*2048 ints = 128 KB
constexpr size_t XGT_OFF  = LIST_OFF + (size_t)16 * 2048 * 4;   // 2 MB bf16 [B][D]
constexpr size_t XGR_OFF  = XGT_OFF + (size_t)B_ * D_ * 2;      // 2 MB bf16 [B][D]

static __device__ __forceinline__ short f2bf(float x) {
    __hip_bfloat16 h = __float2bfloat16(x);
    return *(short*)&h;
}
static __device__ __forceinline__ float gelu_exact(float x) {
    return 0.5f * x * (1.f + erff(x * 0.70710678118654752f));
}

// ---------------- kernel 1: router + log_softmax + argmax + compaction + x gather ----------------
__global__ __launch_bounds__(1024) void k_router_sm(
    const float* __restrict__ ldt, const float* __restrict__ ldr,
    const float* __restrict__ w,   const float* __restrict__ bsc,
    float* __restrict__ sld, int* __restrict__ count, int* __restrict__ list,
    unsigned short* __restrict__ xgt, unsigned short* __restrict__ xgr,
    float* __restrict__ pose)
{
    const int b    = blockIdx.x;
    const int wave = threadIdx.x >> 6;
    const int lane = threadIdx.x & 63;

    __shared__ float lgs[S_];
    __shared__ int   smi;

    // zero this sample's pose slots (replaces a 57KB memset dispatch)
    if (threadIdx.x < 7) pose[(size_t)b * 7 + threadIdx.x] = 0.f;

    const float4* pt = (const float4*)(ldt + ((size_t)b * S_ + wave) * D_);
    const float4* pr = (const float4*)(ldr + ((size_t)b * S_ + wave) * D_);
    const float4* wt = (const float4*)(w);
    const float4* wr = (const float4*)(w + D_);

    float acc = 0.f;
    #pragma unroll
    for (int it = 0; it < 2; it++) {
        const int i = lane + it * 64;
        float4 a  = pt[i]; float4 ww = wt[i];
        acc += a.x * ww.x + a.y * ww.y + a.z * ww.z + a.w * ww.w;
        float4 c  = pr[i]; float4 w2 = wr[i];
        acc += c.x * w2.x + c.y * w2.y + c.z * w2.z + c.w * w2.w;
    }
    #pragma unroll
    for (int off = 32; off > 0; off >>= 1) acc += __shfl_down(acc, off, 64);
    if (lane == 0) lgs[wave] = acc;
    __syncthreads();

    if (threadIdx.x < S_) {
        const int s = threadIdx.x;
        const float v = lgs[s] + bsc[0];
        float mv = v; int mi = s;
        #pragma unroll
        for (int d = 1; d < 16; d <<= 1) {
            float ov = __shfl_xor(mv, d, 16);
            int   oi = __shfl_xor(mi, d, 16);
            if (ov > mv || (ov == mv && oi < mi)) { mv = ov; mi = oi; }
        }
        float sum = expf(v - mv);
        #pragma unroll
        for (int d = 1; d < 16; d <<= 1) sum += __shfl_xor(sum, d, 16);
        const float lse = mv + logf(sum);
        sld[b * S_ + s] = v - lse;
        if (s == 0) {
            smi = mi;
            const int pos = atomicAdd(&count[mi], 1);
            list[mi * B_ + pos] = b;
        }
    }
    __syncthreads();

    const int mi = smi;
    const int t = threadIdx.x;
    if (t < D_) {
        xgt[(size_t)b * D_ + t] = (unsigned short)f2bf(ldt[((size_t)b * S_ + mi) * D_ + t]);
    } else {
        const int t2 = t - D_;
        xgr[(size_t)b * D_ + t2] = (unsigned short)f2bf(ldr[((size_t)b * S_ + mi) * D_ + t2]);
    }
}

// ---------------- kernel 2: tile-list compaction ----------------
__global__ void k_tiles(const int* __restrict__ count, int* __restrict__ ntile,
                        int* __restrict__ tlist)
{
    if (threadIdx.x == 0 && blockIdx.x == 0) {
        int nt = 0;
        for (int m = 0; m < S_; m++) {
            const int c = count[m];
            const int nst = (c + 63) >> 6;
            for (int s2 = 0; s2 < nst; s2++) tlist[nt++] = m | (s2 << 8);
        }
        ntile[0] = nt;
    }
}

// ---------------- kernel 3: expert heads — coalesced LDS weight stream + MFMA ----------------
// bid = t(6) | head(1) | ct(4);  BN=64 ch per block, BK=256 k-halves
__global__ __launch_bounds__(256) void k_expert(
    const float* __restrict__ Wht, const float* __restrict__ bht,
    const float* __restrict__ Wot, const float* __restrict__ bot,
    const float* __restrict__ Whr, const float* __restrict__ bhr,
    const float* __restrict__ Wor, const float* __restrict__ bor,
    const unsigned short* __restrict__ xgt, const unsigned short* __restrict__ xgr,
    const int* __restrict__ count, const int* __restrict__ list,
    const int* __restrict__ ntile, const int* __restrict__ tlist,
    float* __restrict__ pose)
{
    const int bid  = blockIdx.x;
    const int ct   = bid & 15;
    const int head = (bid >> 4) & 1;
    const int t    = bid >> 5;
    if (t >= ntile[0]) return;
    const int tv = tlist[t];
    const int m  = tv & 255;
    const int st = tv >> 8;
    const int n  = count[m];

    const unsigned short* __restrict__ xg = head ? xgr : xgt;
    const float* __restrict__ Wh = head ? Whr : Wht;
    const float* __restrict__ bh = head ? bhr : bht;
    const float* __restrict__ Wo = head ? Wor : Wot;
    const float* __restrict__ bo = head ? bor : bot;
    const int noj    = head ? 4 : 3;
    const int jobase = head ? 3 : 0;
    const int ch0    = ct * 64;

    __shared__ short Bs[64 * 256];     // 32 KB, swizzled [ch][k] bf16
    __shared__ float ored[64][4];

    const int tid  = threadIdx.x;
    const int wave = tid >> 6;
    const int lane = tid & 63;
    const int l15  = lane & 15;
    const int lq   = lane >> 4;
    const int chw  = wave * 16 + l15;  // this lane's ch (local) for MFMA B / epilogue

    ((float*)ored)[tid] = 0.f;

    // A row pointers (lq*8 k-offset baked in)
    const unsigned short* arow[4];
    #pragma unroll
    for (int fm = 0; fm < 4; fm++) {
        const int gi = st * 64 + fm * 16 + l15;
        const int bb = (gi < n) ? list[m * B_ + gi] : 0;
        arow[fm] = xg + (size_t)bb * D_ + lq * 8;
    }

    f32x4 acc[4] = {};

    #pragma unroll
    for (int kh = 0; kh < 2; kh++) {
        const int k0 = kh * 256;
        // ---- stage: wave w loads rows k0+w*64 .. +63, lane = ch; coalesced 256B/instr ----
        const float* wrow = Wh + (size_t)m * D_ * CH_ + (size_t)(k0 + wave * 64) * CH_ + ch0 + lane;
        #pragma unroll 2
        for (int j0 = 0; j0 < 64; j0 += 8) {
            float v[8];
            #pragma unroll
            for (int j = 0; j < 8; j++) v[j] = wrow[(size_t)(j0 + j) * CH_];
            #pragma unroll
            for (int j = 0; j < 8; j++) {
                const int k2 = (wave * 64 + j0 + j) * 2;
                *(short*)((char*)Bs + lane * 512 + (k2 ^ ((lane & 31) << 4))) = f2bf(v[j]);
            }
        }
        __syncthreads();

        // ---- MFMA: 8 k-steps of 32 ----
        #pragma unroll
        for (int t8 = 0; t8 < 8; t8++) {
            const bf16x8 bv = *(const bf16x8*)((char*)Bs + chw * 512 +
                                ((t8 * 64 + lq * 16) ^ ((chw & 31) << 4)));
            #pragma unroll
            for (int fm = 0; fm < 4; fm++) {
                const bf16x8 a = *(const bf16x8*)(arow[fm] + k0 + t8 * 32);
                acc[fm] = __builtin_amdgcn_mfma_f32_16x16x32_bf16(a, bv, acc[fm], 0, 0, 0);
            }
        }
        __syncthreads();
    }

    // ---- epilogue: bias + GELU + Wo partial, 16-lane reduce, LDS combine ----
    const int ch = ch0 + chw;
    const float bias = bh[m * CH_ + ch];
    float wo_l[4];
    #pragma unroll
    for (int jo = 0; jo < 4; jo++)
        wo_l[jo] = (jo < noj) ? Wo[(size_t)(m * CH_ + ch) * noj + jo] : 0.f;

    #pragma unroll
    for (int fm = 0; fm < 4; fm++) {
        #pragma unroll
        for (int j = 0; j < 4; j++) {
            const float g = gelu_exact(acc[fm][j] + bias);
            #pragma unroll
            for (int jo = 0; jo < 4; jo++) {
                if (jo >= noj) continue;
                float v = g * wo_l[jo];
                #pragma unroll
                for (int d = 1; d < 16; d <<= 1) v += __shfl_xor(v, d, 16);
                if (l15 == 0)
                    atomicAdd(&ored[fm * 16 + lq * 4 + j][jo], v);
            }
        }
    }
    __syncthreads();

    // drain: one global atomic per (row, jo)
    if (tid < 64 * 4) {
        const int rl = tid >> 2;
        const int jo = tid & 3;
        const int gi = st * 64 + rl;
        if (jo < noj && gi < n) {
            const int bb = list[m * B_ + gi];
            float v = ored[rl][jo];
            if (ct == 0) v += bo[m * noj + jo];
            atomicAdd(&pose[(size_t)bb * 7 + jobase + jo], v);
        }
    }
}

// ---------------- launch ----------------
extern "C" void kernel_launch(void* const* d_in, const int* in_sizes, int n_in,
                              void* d_out, int out_size, void* d_ws, size_t ws_size,
                              hipStream_t stream)
{
    const float* ldt = (const float*)d_in[0];
    const float* ldr = (const float*)d_in[1];
    const float* wsc = (const float*)d_in[2];
    const float* bsc = (const float*)d_in[3];
    const float* Wht = (const float*)d_in[4];
    const float* bht = (const float*)d_in[5];
    const float* Wot = (const float*)d_in[6];
    const float* bot = (const float*)d_in[7];
    const float* Whr = (const float*)d_in[8];
    const float* bhr = (const float*)d_in[9];
    const float* Wor = (const float*)d_in[10];
    const float* bor = (const float*)d_in[11];

    float* pose = (float*)d_out;                   // [B,7]
    float* sld  = (float*)d_out + (size_t)B_ * 7;  // [B,16]

    int* count = (int*)((char*)d_ws + CNT_OFF);
    int* ntile = (int*)((char*)d_ws + NT_OFF);
    int* tlist = (int*)((char*)d_ws + TL_OFF);
    int* list  = (int*)((char*)d_ws + LIST_OFF);
    unsigned short* xgt = (unsigned short*)((char*)d_ws + XGT_OFF);
    unsigned short* xgr = (unsigned short*)((char*)d_ws + XGR_OFF);

    hipMemsetAsync(count, 0, 16 * sizeof(int), stream);

    // 1) router + softmax + argmax + compaction + bf16 gather (+ pose zeroing)
    k_router_sm<<<dim3(B_), dim3(1024), 0, stream>>>(
        ldt, ldr, wsc, bsc, sld, count, list, xgt, xgr, pose);

    // 2) compact tile list (<= 48 tiles)
    k_tiles<<<dim3(1), dim3(64), 0, stream>>>(count, ntile, tlist);

    // 3) expert heads: grid = 48 tile slots x 2 heads x 16 ch-stripes
    k_expert<<<dim3(48 * 2 * 16), dim3(256), 0, stream>>>(
        Wht, bht, Wot, bot, Whr, bhr, Wor, bor,
        xgt, xgr, count, list, ntile, tlist, pose);
}

// Round 8
// 78.125 us; speedup vs baseline: 1.6747x; 1.4450x over previous
//
#include <hip/hip_runtime.h>
#include <hip/hip_bf16.h>
#include <math.h>

constexpr int B_  = 2048;
constexpr int S_  = 16;
constexpr int D_  = 512;
constexpr int CH_ = 1024;

typedef __attribute__((ext_vector_type(8))) short bf16x8;
typedef __attribute__((ext_vector_type(4))) float f32x4;

// ---------------- workspace layout ----------------
constexpr size_t CNT_OFF  = 0;                                  // 16 ints
constexpr size_t NT_OFF   = 64;                                 // 1 int
constexpr size_t TL_OFF   = 128;                                // 64 ints
constexpr size_t LIST_OFF = 512;                                // 16*2048 ints = 128 KB
constexpr size_t XGT_OFF  = LIST_OFF + (size_t)16 * 2048 * 4;   // 2 MB bf16 [B][D]
constexpr size_t XGR_OFF  = XGT_OFF + (size_t)B_ * D_ * 2;      // 2 MB bf16 [B][D]

static __device__ __forceinline__ short f2bf(float x) {
    __hip_bfloat16 h = __float2bfloat16(x);
    return *(short*)&h;
}
static __device__ __forceinline__ float gelu_exact(float x) {
    return 0.5f * x * (1.f + erff(x * 0.70710678118654752f));
}

// async global -> LDS, 16 bytes per lane (global addr per-lane, LDS dest wave-uniform + lane*16)
static __device__ __forceinline__ void gl_lds16(const void* g, void* l) {
    __builtin_amdgcn_global_load_lds(
        (const __attribute__((address_space(1))) void*)g,
        (__attribute__((address_space(3))) void*)l,
        16, 0, 0);
}

// ---------------- kernel 1: router + log_softmax + argmax + compaction + x gather ----------------
__global__ __launch_bounds__(1024) void k_router_sm(
    const float* __restrict__ ldt, const float* __restrict__ ldr,
    const float* __restrict__ w,   const float* __restrict__ bsc,
    float* __restrict__ sld, int* __restrict__ count, int* __restrict__ list,
    unsigned short* __restrict__ xgt, unsigned short* __restrict__ xgr,
    float* __restrict__ pose)
{
    const int b    = blockIdx.x;
    const int wave = threadIdx.x >> 6;
    const int lane = threadIdx.x & 63;

    __shared__ float lgs[S_];
    __shared__ int   smi;

    if (threadIdx.x < 7) pose[(size_t)b * 7 + threadIdx.x] = 0.f;

    const float4* pt = (const float4*)(ldt + ((size_t)b * S_ + wave) * D_);
    const float4* pr = (const float4*)(ldr + ((size_t)b * S_ + wave) * D_);
    const float4* wt = (const float4*)(w);
    const float4* wr = (const float4*)(w + D_);

    float acc = 0.f;
    #pragma unroll
    for (int it = 0; it < 2; it++) {
        const int i = lane + it * 64;
        float4 a  = pt[i]; float4 ww = wt[i];
        acc += a.x * ww.x + a.y * ww.y + a.z * ww.z + a.w * ww.w;
        float4 c  = pr[i]; float4 w2 = wr[i];
        acc += c.x * w2.x + c.y * w2.y + c.z * w2.z + c.w * w2.w;
    }
    #pragma unroll
    for (int off = 32; off > 0; off >>= 1) acc += __shfl_down(acc, off, 64);
    if (lane == 0) lgs[wave] = acc;
    __syncthreads();

    if (threadIdx.x < S_) {
        const int s = threadIdx.x;
        const float v = lgs[s] + bsc[0];
        float mv = v; int mi = s;
        #pragma unroll
        for (int d = 1; d < 16; d <<= 1) {
            float ov = __shfl_xor(mv, d, 16);
            int   oi = __shfl_xor(mi, d, 16);
            if (ov > mv || (ov == mv && oi < mi)) { mv = ov; mi = oi; }
        }
        float sum = expf(v - mv);
        #pragma unroll
        for (int d = 1; d < 16; d <<= 1) sum += __shfl_xor(sum, d, 16);
        const float lse = mv + logf(sum);
        sld[b * S_ + s] = v - lse;
        if (s == 0) {
            smi = mi;
            const int pos = atomicAdd(&count[mi], 1);
            list[mi * B_ + pos] = b;
        }
    }
    __syncthreads();

    const int mi = smi;
    const int t = threadIdx.x;
    if (t < D_) {
        xgt[(size_t)b * D_ + t] = (unsigned short)f2bf(ldt[((size_t)b * S_ + mi) * D_ + t]);
    } else {
        const int t2 = t - D_;
        xgr[(size_t)b * D_ + t2] = (unsigned short)f2bf(ldr[((size_t)b * S_ + mi) * D_ + t2]);
    }
}

// ---------------- kernel 2: tile-list compaction ----------------
__global__ void k_tiles(const int* __restrict__ count, int* __restrict__ ntile,
                        int* __restrict__ tlist)
{
    if (threadIdx.x == 0 && blockIdx.x == 0) {
        int nt = 0;
        for (int m = 0; m < S_; m++) {
            const int c = count[m];
            const int nst = (c + 63) >> 6;
            for (int s2 = 0; s2 < nst; s2++) tlist[nt++] = m | (s2 << 8);
        }
        ntile[0] = nt;
    }
}

// ---------------- kernel 3: expert heads — global_load_lds staged MFMA ----------------
// bid = t(6) | head(1) | ct(4);  BM=64 x BN=64 x BK=64, 8 K-tiles
__global__ __launch_bounds__(256) void k_expert(
    const float* __restrict__ Wht, const float* __restrict__ bht,
    const float* __restrict__ Wot, const float* __restrict__ bot,
    const float* __restrict__ Whr, const float* __restrict__ bhr,
    const float* __restrict__ Wor, const float* __restrict__ bor,
    const unsigned short* __restrict__ xgt, const unsigned short* __restrict__ xgr,
    const int* __restrict__ count, const int* __restrict__ list,
    const int* __restrict__ ntile, const int* __restrict__ tlist,
    float* __restrict__ pose)
{
    const int bid  = blockIdx.x;
    const int ct   = bid & 15;
    const int head = (bid >> 4) & 1;
    const int t    = bid >> 5;
    if (t >= ntile[0]) return;
    const int tv = tlist[t];
    const int m  = tv & 255;
    const int st = tv >> 8;
    const int n  = count[m];

    const unsigned short* __restrict__ xg = head ? xgr : xgt;
    const float* __restrict__ Wh = head ? Whr : Wht;
    const float* __restrict__ bh = head ? bhr : bht;
    const float* __restrict__ Wo = head ? Wor : Wot;
    const float* __restrict__ bo = head ? bor : bot;
    const int noj    = head ? 4 : 3;
    const int jobase = head ? 3 : 0;
    const int ch0    = ct * 64;

    __shared__ short As[64 * 64];    //  8 KB bf16, source-swizzled k-chunks
    __shared__ float Bsf[64 * 64];   // 16 KB f32 linear [k][ch]
    __shared__ float ored[64][4];    //  1 KB
    __shared__ int   bidx[64];

    const int tid  = threadIdx.x;
    const int wave = tid >> 6;
    const int lane = tid & 63;
    const int l15  = lane & 15;
    const int lq   = lane >> 4;
    const int wr   = wave >> 1, wc = wave & 1;
    const int rbase = wr * 32, cbase = wc * 32;

    if (tid < 64) {
        const int gi = st * 64 + tid;
        bidx[tid] = (gi < n) ? list[m * B_ + gi] : list[m * B_];
    }
    ((float*)ored)[tid] = 0.f;
    __syncthreads();

    // per-lane async-staging source pointers
    // A: instr q = wave*2+i covers rows q*8..q*8+7; lane -> row q*8+(l>>3), swizzled kchunk
    const unsigned short* gA[2];
    #pragma unroll
    for (int i = 0; i < 2; i++) {
        const int r = (wave * 2 + i) * 8 + (lane >> 3);
        const int c = (lane & 7) ^ (r & 7);
        gA[i] = xg + (size_t)bidx[r] * D_ + c * 8;
    }
    // B: instr q2 = wave*4+i covers k-rows q2*4..q2*4+3; lane -> row q2*4+(l>>4), ch (l&15)*4
    const float* gB[4];
    #pragma unroll
    for (int i = 0; i < 4; i++) {
        const int q2 = wave * 4 + i;
        gB[i] = Wh + (size_t)m * D_ * CH_ + (size_t)(q2 * 4 + (lane >> 4)) * CH_ + ch0 + (l15 * 4);
    }

    f32x4 acc[2][2] = {};

    for (int kt = 0; kt < 8; kt++) {
        const int k0 = kt * 64;
        // ---- issue async stages (no VGPR round-trip) ----
        #pragma unroll
        for (int i = 0; i < 2; i++)
            gl_lds16(gA[i] + k0, &As[(wave * 2 + i) * 512]);
        #pragma unroll
        for (int i = 0; i < 4; i++)
            gl_lds16(gB[i] + (size_t)k0 * CH_, &Bsf[(wave * 4 + i) * 256]);
        __syncthreads();   // compiler emits vmcnt(0) drain before barrier

        // ---- MFMA over BK=64 ----
        #pragma unroll
        for (int ks = 0; ks < 2; ks++) {
            bf16x8 a[2];
            #pragma unroll
            for (int fm = 0; fm < 2; fm++) {
                const int r = rbase + fm * 16 + l15;
                const int u = ks * 4 + lq;
                a[fm] = *(const bf16x8*)&As[r * 64 + ((u ^ (r & 7)) << 3)];
            }
            bf16x8 bv[2];
            #pragma unroll
            for (int fn = 0; fn < 2; fn++) {
                const int c = cbase + fn * 16 + l15;
                const int kb = ks * 32 + lq * 8;
                short tmp[8];
                #pragma unroll
                for (int j = 0; j < 8; j++) tmp[j] = f2bf(Bsf[(kb + j) * 64 + c]);
                bv[fn] = *(bf16x8*)tmp;
            }
            #pragma unroll
            for (int fm = 0; fm < 2; fm++)
                #pragma unroll
                for (int fn = 0; fn < 2; fn++)
                    acc[fm][fn] = __builtin_amdgcn_mfma_f32_16x16x32_bf16(a[fm], bv[fn], acc[fm][fn], 0, 0, 0);
        }
        __syncthreads();
    }

    // ---- epilogue: bias + GELU + Wo partial, 16-lane reduce, LDS combine ----
    float g[2][2][4];
    float wo_l[2][4];
    #pragma unroll
    for (int fn = 0; fn < 2; fn++) {
        const int ch = ch0 + cbase + fn * 16 + l15;
        const float bias = bh[m * CH_ + ch];
        #pragma unroll
        for (int fm = 0; fm < 2; fm++)
            #pragma unroll
            for (int j = 0; j < 4; j++)
                g[fm][fn][j] = gelu_exact(acc[fm][fn][j] + bias);
        #pragma unroll
        for (int jo = 0; jo < 4; jo++)
            wo_l[fn][jo] = (jo < noj) ? Wo[(size_t)(m * CH_ + ch) * noj + jo] : 0.f;
    }

    #pragma unroll
    for (int fm = 0; fm < 2; fm++) {
        #pragma unroll
        for (int j = 0; j < 4; j++) {
            const int rl = rbase + fm * 16 + lq * 4 + j;
            #pragma unroll
            for (int jo = 0; jo < 4; jo++) {
                if (jo >= noj) continue;
                float v = g[fm][0][j] * wo_l[0][jo] + g[fm][1][j] * wo_l[1][jo];
                #pragma unroll
                for (int d = 1; d < 16; d <<= 1) v += __shfl_xor(v, d, 16);
                if (l15 == 0)
                    atomicAdd(&ored[rl][jo], v);
            }
        }
    }
    __syncthreads();

    // drain: one global atomic per (row, jo)
    {
        const int rl = tid >> 2;
        const int jo = tid & 3;
        const int gi = st * 64 + rl;
        if (jo < noj && gi < n) {
            const int bb = list[m * B_ + gi];
            float v = ored[rl][jo];
            if (ct == 0) v += bo[m * noj + jo];
            atomicAdd(&pose[(size_t)bb * 7 + jobase + jo], v);
        }
    }
}

// ---------------- launch ----------------
extern "C" void kernel_launch(void* const* d_in, const int* in_sizes, int n_in,
                              void* d_out, int out_size, void* d_ws, size_t ws_size,
                              hipStream_t stream)
{
    const float* ldt = (const float*)d_in[0];
    const float* ldr = (const float*)d_in[1];
    const float* wsc = (const float*)d_in[2];
    const float* bsc = (const float*)d_in[3];
    const float* Wht = (const float*)d_in[4];
    const float* bht = (const float*)d_in[5];
    const float* Wot = (const float*)d_in[6];
    const float* bot = (const float*)d_in[7];
    const float* Whr = (const float*)d_in[8];
    const float* bhr = (const float*)d_in[9];
    const float* Wor = (const float*)d_in[10];
    const float* bor = (const float*)d_in[11];

    float* pose = (float*)d_out;                   // [B,7]
    float* sld  = (float*)d_out + (size_t)B_ * 7;  // [B,16]

    int* count = (int*)((char*)d_ws + CNT_OFF);
    int* ntile = (int*)((char*)d_ws + NT_OFF);
    int* tlist = (int*)((char*)d_ws + TL_OFF);
    int* list  = (int*)((char*)d_ws + LIST_OFF);
    unsigned short* xgt = (unsigned short*)((char*)d_ws + XGT_OFF);
    unsigned short* xgr = (unsigned short*)((char*)d_ws + XGR_OFF);

    (void)hipMemsetAsync(count, 0, 16 * sizeof(int), stream);

    // 1) router + softmax + argmax + compaction + bf16 gather (+ pose zeroing)
    k_router_sm<<<dim3(B_), dim3(1024), 0, stream>>>(
        ldt, ldr, wsc, bsc, sld, count, list, xgt, xgr, pose);

    // 2) compact tile list (<= 48 tiles)
    k_tiles<<<dim3(1), dim3(64), 0, stream>>>(count, ntile, tlist);

    // 3) expert heads: grid = 48 tile slots x 2 heads x 16 ch-stripes
    k_expert<<<dim3(48 * 2 * 16), dim3(256), 0, stream>>>(
        Wht, bht, Wot, bot, Whr, bhr, Wor, bor,
        xgt, xgr, count, list, ntile, tlist, pose);
}